// Round 11
// baseline (216.730 us; speedup 1.0000x reference)
//
#include <hip/hip_runtime.h>

// ---------------------------------------------------------------------------
// TextGraphSAGE: 2-layer SAGEConv (mean aggr), N=50000, D=768, H=128, C=4,
// E=800000.
//  - project BEFORE aggregating (mean commutes with linear map)
//  - CSR gather instead of scatter atomics (r1: 102M float atomics = 77%)
//  - r6/r10 lessons: gemm is latency-bound (MfmaUtil 6.6%, 1.46TB/s), the
//    2-barrier reg-stage+convert structure exposes HBM latency per K-tile.
//  - r11: x pre-converted to bf16 (fused into csr_count); gemm A-staging via
//    __builtin_amdgcn_global_load_lds (async, width 16) into double-buffered
//    LDS, ONE barrier per K-tile. Linear LDS dest + inverse-swizzled global
//    source + same-XOR read (chunk ^= row&7) -> 2-way banks (free).
// ---------------------------------------------------------------------------

typedef __bf16 bf16x8 __attribute__((ext_vector_type(8)));
typedef float  f32x4  __attribute__((ext_vector_type(4)));

__device__ __forceinline__ float bf16_lo(uint32_t w) {
    union { uint32_t u; float f; } c; c.u = w << 16; return c.f;
}
__device__ __forceinline__ float bf16_hi(uint32_t w) {
    union { uint32_t u; float f; } c; c.u = w & 0xffff0000u; return c.f;
}

__device__ __forceinline__ void load_lds16(const void* g, void* l) {
    __builtin_amdgcn_global_load_lds(
        (const __attribute__((address_space(1))) void*)g,
        (__attribute__((address_space(3))) void*)l, 16, 0, 0);
}

// ---- prep: pack W into fragment-major bf16 Bp[kg][col][8] (kg=k/8, 96x256x8)
//      element (col,k) -> Bp[(k>>3)*2048 + col*8 + (k&7)]; also zero deg.
__global__ __launch_bounds__(256)
void prep(const float* __restrict__ W1l, const float* __restrict__ W1r,
          __bf16* __restrict__ Bp, int* __restrict__ deg, int N)
{
    int i = blockIdx.x * 256 + threadIdx.x;
    if (i < N) deg[i] = 0;
    if (i < 256 * 768) {
        int col = i / 768, k = i - col * 768;
        float v = (col < 128) ? W1l[col * 768 + k] : W1r[(col - 128) * 768 + k];
        Bp[((k >> 3) << 11) + (col << 3) + (k & 7)] = (__bf16)v;
    }
}

// ---- fused: x -> bf16 conversion (BW-bound) + degree histogram (latency-
// bound atomics) -- the two overlap. cblocks conversion blocks first.
__global__ __launch_bounds__(256)
void cvt_count(const float* __restrict__ x, __bf16* __restrict__ xb, int nu8,
               const int* __restrict__ ei, int* __restrict__ deg, int E,
               int cblocks)
{
    if ((int)blockIdx.x < cblocks) {
        int stride = cblocks * 256;
        for (int u = blockIdx.x * 256 + threadIdx.x; u < nu8; u += stride) {
            const float* src = x + (size_t)u * 8;
            float4 f0 = *(const float4*)src;
            float4 f1 = *(const float4*)(src + 4);
            bf16x8 b;
            b[0] = (__bf16)f0.x; b[1] = (__bf16)f0.y;
            b[2] = (__bf16)f0.z; b[3] = (__bf16)f0.w;
            b[4] = (__bf16)f1.x; b[5] = (__bf16)f1.y;
            b[6] = (__bf16)f1.z; b[7] = (__bf16)f1.w;
            *(bf16x8*)(xb + (size_t)u * 8) = b;
        }
    } else {
        int e = (blockIdx.x - cblocks) * 256 + threadIdx.x;
        if (e < E) atomicAdd(&deg[ei[E + e]], 1);
    }
}

// ---- scan step 1: per-1024-block exclusive scan + block totals
__global__ __launch_bounds__(1024)
void scan1(const int* __restrict__ deg, int* __restrict__ row_ptr,
           int* __restrict__ partials, int N)
{
    __shared__ int buf[1024];
    int i = blockIdx.x * 1024 + threadIdx.x;
    int v = (i < N) ? deg[i] : 0;
    int val = v;
    buf[threadIdx.x] = val;
    __syncthreads();
    for (int off = 1; off < 1024; off <<= 1) {
        int t = (threadIdx.x >= (unsigned)off) ? buf[threadIdx.x - off] : 0;
        __syncthreads();
        val += t;
        buf[threadIdx.x] = val;
        __syncthreads();
    }
    if (i < N) row_ptr[i] = val - v;
    if (threadIdx.x == 1023) partials[blockIdx.x] = val;
}

// ---- scan steps 2+3 merged
__global__ __launch_bounds__(1024)
void scan23(int* __restrict__ row_ptr, int* __restrict__ cursor,
            const int* __restrict__ partials, int N, int E, int nb)
{
    __shared__ int soff;
    int b = blockIdx.x;
    if (threadIdx.x < 64) {
        int lane = threadIdx.x;
        int v = (lane < nb) ? partials[lane] : 0;
        int s = v;
        #pragma unroll
        for (int off = 1; off < 64; off <<= 1) {
            int t = __shfl_up(s, off);
            if (lane >= off) s += t;
        }
        if (lane == b) soff = s - v;
    }
    __syncthreads();
    int off = soff;
    int i = b * 1024 + threadIdx.x;
    if (i < N) {
        int v = row_ptr[i] + off;
        row_ptr[i] = v;
        cursor[i]  = v;
    }
    if (b == 0 && threadIdx.x == 0) row_ptr[N] = E;
}

// ---- fused: gemm tiles (blocks < mtiles) + csr_fill (blocks >= mtiles).
// gemm: pq[M][256](bf16) = xb[M][768] @ W[256][768]^T. 64x256 tile, 8 waves
// (2x4, 32x64 each), BK=128. A staged via global_load_lds into As[2][64][128]
// (double buffer, one barrier/tile). Source pre-swizzled: LDS[row][chunk c]
// holds global chunk (c ^ (row&7)); reader XORs the same way.
__global__ __launch_bounds__(512)
void gemm_fill(const __bf16* __restrict__ xb, const __bf16* __restrict__ Bp,
               __bf16* __restrict__ Cb, int M, int mtiles,
               const int* __restrict__ ei, int* __restrict__ cursor,
               int* __restrict__ csr_src, int E)
{
    __shared__ __bf16 As[2][64][128];        // 32 KB, linear (swizzled content)
    const int tid = threadIdx.x;

    if ((int)blockIdx.x >= mtiles) {
        // ---------------- csr_fill path ----------------
        int stride = (gridDim.x - mtiles) * 512;
        for (int e = (blockIdx.x - mtiles) * 512 + tid; e < E; e += stride) {
            int src = ei[e];
            int dst = ei[E + e];
            int pos = atomicAdd(&cursor[dst], 1);
            csr_src[pos] = src;
        }
        return;
    }

    // ---------------- gemm path ----------------
    const int bm   = blockIdx.x * 64;
    const int lane = tid & 63;
    const int wave = tid >> 6;               // 0..7
    const int wr = wave >> 2, wc = wave & 3; // wave tile: 32 rows x 64 cols
    const int l15 = lane & 15;
    const int lk  = lane >> 4;               // 0..3

    f32x4 acc[2][4] = {};

    // staging: per wave 2 global_load_lds (64 lanes x 16B = 1KB each).
    // instruction it covers LDS rows 4*(wave*2+it)..+3; lane's 16B:
    //   row = 4*(wave*2+it) + (lane>>4), lds chunk = lane&15,
    //   global chunk = (lane&15) ^ (row&7)   [inverse swizzle at source]
    const int sr0 = (wave * 2 + 0) * 4 + (lane >> 4);
    const int sr1 = (wave * 2 + 1) * 4 + (lane >> 4);
    const int sc  = lane & 15;
    const __bf16* g0 = xb + (size_t)(bm + sr0) * 768 + (((sc ^ (sr0 & 7))) << 3);
    const __bf16* g1 = xb + (size_t)(bm + sr1) * 768 + (((sc ^ (sr1 & 7))) << 3);
    // rows bm+sr >= M read the padded tail of xb (finite poison, never stored)

    const __bf16* bbase = Bp + ((size_t)(wc * 64 + l15) << 3) + ((size_t)lk << 11);

    // prologue: stage tile 0 into buf 0
    load_lds16(g0, &As[0][(wave * 2 + 0) * 4][0]);
    load_lds16(g1, &As[0][(wave * 2 + 1) * 4][0]);
    __syncthreads();                         // vmcnt(0) drain: buf0 ready

    int cur = 0;
    for (int kt = 0; kt < 6; ++kt) {
        if (kt < 5) {                        // async stage next tile -> buf^1
            load_lds16(g0 + (kt + 1) * 128, &As[cur ^ 1][(wave * 2 + 0) * 4][0]);
            load_lds16(g1 + (kt + 1) * 128, &As[cur ^ 1][(wave * 2 + 1) * 4][0]);
        }

        #pragma unroll
        for (int ksp = 0; ksp < 2; ++ksp) {  // two ks-pairs: caps B VGPRs
            bf16x8 bcur[2][4];
            #pragma unroll
            for (int k2 = 0; k2 < 2; ++k2)
                #pragma unroll
                for (int j = 0; j < 4; ++j)
                    bcur[k2][j] = *(const bf16x8*)(bbase +
                        (((size_t)(kt * 16 + (ksp * 2 + k2) * 4) << 11) +
                         ((size_t)j << 7)));          // kg: lk lives in bbase
            #pragma unroll
            for (int k2 = 0; k2 < 2; ++k2) {
                int koff = (ksp * 2 + k2) * 32 + lk * 8;
                bf16x8 af[2];
                #pragma unroll
                for (int i = 0; i < 2; ++i) {
                    int r = wr * 32 + i * 16 + l15;
                    af[i] = *(const bf16x8*)&As[cur][r][koff ^ ((r & 7) << 3)];
                }
                #pragma unroll
                for (int i = 0; i < 2; ++i)
                    #pragma unroll
                    for (int j = 0; j < 4; ++j)
                        acc[i][j] = __builtin_amdgcn_mfma_f32_16x16x32_bf16(
                            af[i], bcur[k2][j], acc[i][j], 0, 0, 0);
            }
        }

        __syncthreads();   // drains next-tile stage (vmcnt 0) + LDS reads done
        cur ^= 1;
    }

    // C/D layout: col = lane&15, row = (lane>>4)*4 + reg  [m89-verified]
    #pragma unroll
    for (int i = 0; i < 2; ++i)
        #pragma unroll
        for (int j = 0; j < 4; ++j)
            #pragma unroll
            for (int v = 0; v < 4; ++v) {
                int row = bm + wr * 32 + i * 16 + lk * 4 + v;
                int col = wc * 64 + j * 16 + l15;
                if (row < M) Cb[(size_t)row * 256 + col] = (__bf16)acc[i][j][v];
            }
}

// ---- layer 1 + layer-2 projection, fused. One wave per node.
// 8 lanes per edge x 32B/lane (2 x uint4) -> 8 edges in flight / iteration.
__global__ __launch_bounds__(256)
void sage1_fused(const int* __restrict__ row_ptr, const int* __restrict__ csr_src,
                 const __bf16* __restrict__ pq, const float* __restrict__ b1,
                 const float* __restrict__ W2l, const float* __restrict__ W2r,
                 float* __restrict__ r, float* __restrict__ s, int N)
{
    __shared__ float Wl[512], Wr[512];
    for (int i = threadIdx.x; i < 512; i += 256) {
        Wl[i] = W2l[i];
        Wr[i] = W2r[i];
    }
    __syncthreads();

    int wid  = threadIdx.x >> 6;
    int lane = threadIdx.x & 63;
    int g = lane >> 3;          // edge slot 0..7
    int l = lane & 7;           // feature block 0..7
    int n = blockIdx.x * 4 + wid;
    if (n >= N) return;
    int beg = row_ptr[n], end = row_ptr[n + 1];

    float a0[8] = {}, a1[8] = {};   // feats l*8+j and 64+l*8+j
    for (int eb = beg; eb < end; eb += 64) {
        int cnt = min(64, end - eb);
        int id = (eb + lane < end) ? csr_src[eb + lane] : 0;
        for (int t = 0; t < cnt; t += 8) {
            int src = __shfl(id, t + g);
            if (t + g < cnt) {
                const __bf16* row = pq + (size_t)src * 256;
                uint4 w0 = *(const uint4*)(row + l * 8);
                uint4 w1 = *(const uint4*)(row + 64 + l * 8);
                a0[0] += bf16_lo(w0.x); a0[1] += bf16_hi(w0.x);
                a0[2] += bf16_lo(w0.y); a0[3] += bf16_hi(w0.y);
                a0[4] += bf16_lo(w0.z); a0[5] += bf16_hi(w0.z);
                a0[6] += bf16_lo(w0.w); a0[7] += bf16_hi(w0.w);
                a1[0] += bf16_lo(w1.x); a1[1] += bf16_hi(w1.x);
                a1[2] += bf16_lo(w1.y); a1[3] += bf16_hi(w1.y);
                a1[4] += bf16_lo(w1.z); a1[5] += bf16_hi(w1.z);
                a1[6] += bf16_lo(w1.w); a1[7] += bf16_hi(w1.w);
            }
        }
    }
    #pragma unroll
    for (int c = 0; c < 8; ++c) {
        a0[c] += __shfl_xor(a0[c], 8);  a1[c] += __shfl_xor(a1[c], 8);
        a0[c] += __shfl_xor(a0[c], 16); a1[c] += __shfl_xor(a1[c], 16);
        a0[c] += __shfl_xor(a0[c], 32); a1[c] += __shfl_xor(a1[c], 32);
    }

    float inv = 1.0f / fmaxf((float)(end - beg), 1.0f);
    const __bf16* qrow = pq + (size_t)n * 256 + 128;
    uint4  qw0 = *(const uint4*)(qrow + l * 8);
    uint4  qw1 = *(const uint4*)(qrow + 64 + l * 8);
    float4 bv00 = *(const float4*)(b1 + l * 8);
    float4 bv01 = *(const float4*)(b1 + l * 8 + 4);
    float4 bv10 = *(const float4*)(b1 + 64 + l * 8);
    float4 bv11 = *(const float4*)(b1 + 64 + l * 8 + 4);
    float h0[8], h1[8];
    h0[0] = fmaxf(a0[0] * inv + bv00.x + bf16_lo(qw0.x), 0.f);
    h0[1] = fmaxf(a0[1] * inv + bv00.y + bf16_hi(qw0.x), 0.f);
    h0[2] = fmaxf(a0[2] * inv + bv00.z + bf16_lo(qw0.y), 0.f);
    h0[3] = fmaxf(a0[3] * inv + bv00.w + bf16_hi(qw0.y), 0.f);
    h0[4] = fmaxf(a0[4] * inv + bv01.x + bf16_lo(qw0.z), 0.f);
    h0[5] = fmaxf(a0[5] * inv + bv01.y + bf16_hi(qw0.z), 0.f);
    h0[6] = fmaxf(a0[6] * inv + bv01.z + bf16_lo(qw0.w), 0.f);
    h0[7] = fmaxf(a0[7] * inv + bv01.w + bf16_hi(qw0.w), 0.f);
    h1[0] = fmaxf(a1[0] * inv + bv10.x + bf16_lo(qw1.x), 0.f);
    h1[1] = fmaxf(a1[1] * inv + bv10.y + bf16_hi(qw1.x), 0.f);
    h1[2] = fmaxf(a1[2] * inv + bv10.z + bf16_lo(qw1.y), 0.f);
    h1[3] = fmaxf(a1[3] * inv + bv10.w + bf16_hi(qw1.y), 0.f);
    h1[4] = fmaxf(a1[4] * inv + bv11.x + bf16_lo(qw1.z), 0.f);
    h1[5] = fmaxf(a1[5] * inv + bv11.y + bf16_hi(qw1.z), 0.f);
    h1[6] = fmaxf(a1[6] * inv + bv11.z + bf16_lo(qw1.w), 0.f);
    h1[7] = fmaxf(a1[7] * inv + bv11.w + bf16_hi(qw1.w), 0.f);

    float part[8];
    #pragma unroll
    for (int c = 0; c < 4; ++c) {
        float pl = 0.f, pr = 0.f;
        #pragma unroll
        for (int j = 0; j < 8; ++j) {
            pl = fmaf(h0[j], Wl[c * 128 + l * 8 + j], pl);
            pl = fmaf(h1[j], Wl[c * 128 + 64 + l * 8 + j], pl);
            pr = fmaf(h0[j], Wr[c * 128 + l * 8 + j], pr);
            pr = fmaf(h1[j], Wr[c * 128 + 64 + l * 8 + j], pr);
        }
        part[c] = pl; part[4 + c] = pr;
    }
    #pragma unroll
    for (int off = 4; off; off >>= 1)
        #pragma unroll
        for (int c = 0; c < 8; ++c)
            part[c] += __shfl_xor(part[c], off);
    if (lane == 0) {
        *(float4*)(r + (size_t)n * 4) = make_float4(part[0], part[1], part[2], part[3]);
        *(float4*)(s + (size_t)n * 4) = make_float4(part[4], part[5], part[6], part[7]);
    }
}

// ---- layer 2: out[n] = mean_{src} r[src] + b2 + s[n]
__global__ __launch_bounds__(256)
void sage2_gather(const int* __restrict__ row_ptr, const int* __restrict__ csr_src,
                  const float* __restrict__ r, const float* __restrict__ s,
                  const float* __restrict__ b2, float* __restrict__ out, int N)
{
    int t = blockIdx.x * 256 + threadIdx.x;
    if (t >= N * 4) return;
    int n = t >> 2, c = t & 3;
    int beg = row_ptr[n], end = row_ptr[n + 1];
    float acc = 0.f;
    for (int e = beg; e < end; ++e)
        acc += r[(size_t)csr_src[e] * 4 + c];
    out[t] = acc / fmaxf((float)(end - beg), 1.0f) + b2[c] + s[t];
}

extern "C" void kernel_launch(void* const* d_in, const int* in_sizes, int n_in,
                              void* d_out, int out_size, void* d_ws, size_t ws_size,
                              hipStream_t stream)
{
    const float* x   = (const float*)d_in[0];
    const int*   ei  = (const int*)d_in[1];
    const float* W1l = (const float*)d_in[2];
    const float* b1l = (const float*)d_in[3];
    const float* W1r = (const float*)d_in[4];
    const float* W2l = (const float*)d_in[5];
    const float* b2l = (const float*)d_in[6];
    const float* W2r = (const float*)d_in[7];
    float* out = (float*)d_out;

    const int N = in_sizes[0] / 768;   // 50000
    const int E = in_sizes[1] / 2;     // 800000
    const int NB = (N + 1023) / 1024;  // 49 scan blocks
    const int mtiles = (N + 63) / 64;  // 782 gemm tiles
    const int Mpad = mtiles * 64;      // 50048 rows (padded xb)

    char* ws = (char*)d_ws;
    size_t off = 0;
    auto alloc = [&](size_t bytes) -> void* {
        void* pp = ws + off;
        off += (bytes + 255) & ~(size_t)255;
        return pp;
    };
    __bf16* xb      = (__bf16*)alloc((size_t)Mpad * 768 * 2);   // 76.9 MB
    __bf16* pq      = (__bf16*)alloc((size_t)N * 256 * 2);
    float*  r       = (float*)alloc((size_t)N * 4 * 4);
    float*  s       = (float*)alloc((size_t)N * 4 * 4);
    __bf16* Bp      = (__bf16*)alloc((size_t)256 * 768 * 2);
    int*    deg     = (int*)alloc((size_t)N * 4);
    int*    row_ptr = (int*)alloc((size_t)(N + 1) * 4);
    int*    cursor  = (int*)alloc((size_t)N * 4);
    int*    csr_src = (int*)alloc((size_t)E * 4);
    int*    partials= (int*)alloc((size_t)64 * 4);

    // ---- pack W fragment-major + zero deg
    prep<<<(256 * 768 + 255) / 256, 256, 0, stream>>>(W1l, W1r, Bp, deg, N);

    // ---- x -> bf16 (BW-bound) fused with degree histogram (latency-bound)
    const int cblocks = 2048;
    const int nu8 = N * 96;                       // N*768/8 conversion units
    cvt_count<<<cblocks + (E + 255) / 256, 256, 0, stream>>>(
        x, xb, nu8, ei, deg, E, cblocks);

    // ---- scans
    scan1<<<NB, 1024, 0, stream>>>(deg, row_ptr, partials, N);
    scan23<<<NB, 1024, 0, stream>>>(row_ptr, cursor, partials, N, E, NB);

    // ---- fused layer-1 projection (bf16 MFMA, async-staged) + csr_fill
    gemm_fill<<<mtiles + 256, 512, 0, stream>>>(xb, Bp, pq, N, mtiles,
                                                ei, cursor, csr_src, E);

    // ---- layer 1 aggregate + epilogue + layer-2 projection (fused)
    sage1_fused<<<(N + 3) / 4, 256, 0, stream>>>(row_ptr, csr_src, pq, b1l,
                                                 W2l, W2r, r, s, N);

    // ---- layer 2 aggregate + epilogue
    sage2_gather<<<(N * 4 + 255) / 256, 256, 0, stream>>>(row_ptr, csr_src, r, s, b2l, out, N);
}

// Round 12
// 203.779 us; speedup vs baseline: 1.0636x; 1.0636x over previous
//
#include <hip/hip_runtime.h>

// ---------------------------------------------------------------------------
// TextGraphSAGE: 2-layer SAGEConv (mean aggr), N=50000, D=768, H=128, C=4,
// E=800000.
//  - project BEFORE aggregating (mean commutes with linear map)
//  - CSR gather instead of scatter atomics (r1: 102M float atomics = 77%)
//  - r10/r11 lessons: global_load_lds staging fixed the gemm stall (113 ->
//    <84us) but the separate fp32->bf16 pass (230MB) ate the gain.
//  - r12: stage fp32 x DIRECTLY via global_load_lds (no cvt pass, no xb);
//    convert fp32->bf16 during the LDS->VGPR fragment read. 3-buffer
//    depth-2 prefetch with counted vmcnt(2) + raw s_barrier (never drain
//    to 0 in the loop); B loads issued before the stage so the compiler's
//    B-wait keeps the newest prefetch in flight.
// ---------------------------------------------------------------------------

typedef __bf16 bf16x8 __attribute__((ext_vector_type(8)));
typedef float  f32x4  __attribute__((ext_vector_type(4)));

__device__ __forceinline__ float bf16_lo(uint32_t w) {
    union { uint32_t u; float f; } c; c.u = w << 16; return c.f;
}
__device__ __forceinline__ float bf16_hi(uint32_t w) {
    union { uint32_t u; float f; } c; c.u = w & 0xffff0000u; return c.f;
}

__device__ __forceinline__ void load_lds16(const void* g, void* l) {
    __builtin_amdgcn_global_load_lds(
        (const __attribute__((address_space(1))) void*)g,
        (__attribute__((address_space(3))) void*)l, 16, 0, 0);
}

// ---- prep: pack W into fragment-major bf16 Bp[kg][col][8] (kg=k/8, 96x256x8)
//      element (col,k) -> Bp[(k>>3)*2048 + col*8 + (k&7)]; also zero deg.
__global__ __launch_bounds__(256)
void prep(const float* __restrict__ W1l, const float* __restrict__ W1r,
          __bf16* __restrict__ Bp, int* __restrict__ deg, int N)
{
    int i = blockIdx.x * 256 + threadIdx.x;
    if (i < N) deg[i] = 0;
    if (i < 256 * 768) {
        int col = i / 768, k = i - col * 768;
        float v = (col < 128) ? W1l[col * 768 + k] : W1r[(col - 128) * 768 + k];
        Bp[((k >> 3) << 11) + (col << 3) + (k & 7)] = (__bf16)v;
    }
}

// ---- CSR build step 1: degree histogram
__global__ __launch_bounds__(256)
void csr_count(const int* __restrict__ ei, int* __restrict__ deg, int E)
{
    int e = blockIdx.x * 256 + threadIdx.x;
    if (e >= E) return;
    atomicAdd(&deg[ei[E + e]], 1);
}

// ---- scan step 1: per-1024-block exclusive scan + block totals
__global__ __launch_bounds__(1024)
void scan1(const int* __restrict__ deg, int* __restrict__ row_ptr,
           int* __restrict__ partials, int N)
{
    __shared__ int buf[1024];
    int i = blockIdx.x * 1024 + threadIdx.x;
    int v = (i < N) ? deg[i] : 0;
    int val = v;
    buf[threadIdx.x] = val;
    __syncthreads();
    for (int off = 1; off < 1024; off <<= 1) {
        int t = (threadIdx.x >= (unsigned)off) ? buf[threadIdx.x - off] : 0;
        __syncthreads();
        val += t;
        buf[threadIdx.x] = val;
        __syncthreads();
    }
    if (i < N) row_ptr[i] = val - v;
    if (threadIdx.x == 1023) partials[blockIdx.x] = val;
}

// ---- scan steps 2+3 merged
__global__ __launch_bounds__(1024)
void scan23(int* __restrict__ row_ptr, int* __restrict__ cursor,
            const int* __restrict__ partials, int N, int E, int nb)
{
    __shared__ int soff;
    int b = blockIdx.x;
    if (threadIdx.x < 64) {
        int lane = threadIdx.x;
        int v = (lane < nb) ? partials[lane] : 0;
        int s = v;
        #pragma unroll
        for (int off = 1; off < 64; off <<= 1) {
            int t = __shfl_up(s, off);
            if (lane >= off) s += t;
        }
        if (lane == b) soff = s - v;
    }
    __syncthreads();
    int off = soff;
    int i = b * 1024 + threadIdx.x;
    if (i < N) {
        int v = row_ptr[i] + off;
        row_ptr[i] = v;
        cursor[i]  = v;
    }
    if (b == 0 && threadIdx.x == 0) row_ptr[N] = E;
}

// ---- fused: gemm tiles (blocks < mtiles) + csr_fill (blocks >= mtiles).
// gemm: pq[M][256](bf16) = x[M][768](f32) @ W[256][768]^T. 64x256 tile,
// 8 waves (2x4, 32x64 each), BK=64, 12 K-tiles. A staged fp32 via
// global_load_lds into As[3][64][64] (depth-2 prefetch, counted vmcnt(2),
// raw s_barrier -- loop never drains vmcnt to 0). fp32->bf16 conversion
// happens at fragment read. Source-side XOR swizzle (16B chunk ^ row&7),
// linear LDS dest, same XOR on read -> <=2-way banks (free).
__global__ __launch_bounds__(512)
void gemm_fill(const float* __restrict__ x, const __bf16* __restrict__ Bp,
               __bf16* __restrict__ Cb, int M, int mtiles,
               const int* __restrict__ ei, int* __restrict__ cursor,
               int* __restrict__ csr_src, int E)
{
    __shared__ float As[3][64][64];          // 48 KB
    const int tid = threadIdx.x;

    if ((int)blockIdx.x >= mtiles) {
        // ---------------- csr_fill path ----------------
        int stride = (gridDim.x - mtiles) * 512;
        for (int e = (blockIdx.x - mtiles) * 512 + tid; e < E; e += stride) {
            int src = ei[e];
            int dst = ei[E + e];
            int pos = atomicAdd(&cursor[dst], 1);
            csr_src[pos] = src;
        }
        return;
    }

    // ---------------- gemm path ----------------
    const int bm   = blockIdx.x * 64;
    const int lane = tid & 63;
    const int wave = tid >> 6;               // 0..7
    const int wr = wave >> 2, wc = wave & 3; // wave tile: 32 rows x 64 cols
    const int l15 = lane & 15;
    const int lk  = lane >> 4;               // 0..3

    f32x4 acc[2][4] = {};

    // staging: 2 global_load_lds per wave per tile, each 1KB = 4 rows x 256B.
    //   instr it: rows wave*8 + it*4 + (lane>>4); lds 16B-chunk = lane&15;
    //   source chunk = (lane&15) ^ (row&7)   [involution swizzle at source]
    const int sr0 = wave * 8 + (lane >> 4);
    const int sr1 = wave * 8 + 4 + (lane >> 4);
    const int sc  = lane & 15;
    const float* g0 = x + (size_t)min(bm + sr0, M - 1) * 768 + ((sc ^ (sr0 & 7)) << 2);
    const float* g1 = x + (size_t)min(bm + sr1, M - 1) * 768 + ((sc ^ (sr1 & 7)) << 2);
    // clamped rows duplicate row M-1 (never stored)

    const __bf16* bbase = Bp + ((size_t)(wc * 64 + l15) << 3) + ((size_t)lk << 11);

    // prologue: stage tiles 0 and 1 (4 loads outstanding)
    load_lds16(g0,      &As[0][wave * 8][0]);
    load_lds16(g1,      &As[0][wave * 8 + 4][0]);
    load_lds16(g0 + 64, &As[1][wave * 8][0]);
    load_lds16(g1 + 64, &As[1][wave * 8 + 4][0]);

    for (int kt = 0; kt < 12; ++kt) {
        // wait own 2 loads of tile kt (leave tile kt+1's in flight), barrier.
        // raw s_barrier does NOT drain vmcnt -> prefetch survives.
        asm volatile("s_waitcnt vmcnt(2)\n\ts_barrier" ::: "memory");
        __builtin_amdgcn_sched_barrier(0);
        const int buf = kt % 3;

        // B fragments for tile kt (L2-resident), issued BEFORE the stage so
        // the compiler's pre-MFMA B-wait keeps the newest prefetch in flight
        bf16x8 bcur[2][4];
        #pragma unroll
        for (int ks = 0; ks < 2; ++ks)
            #pragma unroll
            for (int j = 0; j < 4; ++j)
                bcur[ks][j] = *(const bf16x8*)(bbase +
                    (((size_t)(kt * 8 + ks * 4) << 11) + ((size_t)j << 7)));

        // async stage tile kt+2 into buf (kt+2)%3 (consumed two iters ago)
        if (kt < 10) {
            const int nb = (kt + 2) % 3;
            load_lds16(g0 + (kt + 2) * 64, &As[nb][wave * 8][0]);
            load_lds16(g1 + (kt + 2) * 64, &As[nb][wave * 8 + 4][0]);
        }

        #pragma unroll
        for (int ks = 0; ks < 2; ++ks) {
            bf16x8 af[2];
            #pragma unroll
            for (int i = 0; i < 2; ++i) {
                int r = wr * 32 + i * 16 + l15;
                int sw = r & 7;
                int c0 = (ks * 32 + lk * 8) >> 2;   // global 16B chunk (even)
                float4 lo = *(const float4*)&As[buf][r][((c0)     ^ sw) << 2];
                float4 hi = *(const float4*)&As[buf][r][((c0 + 1) ^ sw) << 2];
                bf16x8 a;
                a[0] = (__bf16)lo.x; a[1] = (__bf16)lo.y;
                a[2] = (__bf16)lo.z; a[3] = (__bf16)lo.w;
                a[4] = (__bf16)hi.x; a[5] = (__bf16)hi.y;
                a[6] = (__bf16)hi.z; a[7] = (__bf16)hi.w;
                af[i] = a;
            }
            #pragma unroll
            for (int i = 0; i < 2; ++i)
                #pragma unroll
                for (int j = 0; j < 4; ++j)
                    acc[i][j] = __builtin_amdgcn_mfma_f32_16x16x32_bf16(
                        af[i], bcur[ks][j], acc[i][j], 0, 0, 0);
        }
    }

    // C/D layout: col = lane&15, row = (lane>>4)*4 + reg  [m89-verified]
    #pragma unroll
    for (int i = 0; i < 2; ++i)
        #pragma unroll
        for (int j = 0; j < 4; ++j)
            #pragma unroll
            for (int v = 0; v < 4; ++v) {
                int row = bm + wr * 32 + i * 16 + lk * 4 + v;
                int col = wc * 64 + j * 16 + l15;
                if (row < M) Cb[(size_t)row * 256 + col] = (__bf16)acc[i][j][v];
            }
}

// ---- layer 1 + layer-2 projection, fused. One wave per node.
// 8 lanes per edge x 32B/lane (2 x uint4) -> 8 edges in flight / iteration.
__global__ __launch_bounds__(256)
void sage1_fused(const int* __restrict__ row_ptr, const int* __restrict__ csr_src,
                 const __bf16* __restrict__ pq, const float* __restrict__ b1,
                 const float* __restrict__ W2l, const float* __restrict__ W2r,
                 float* __restrict__ r, float* __restrict__ s, int N)
{
    __shared__ float Wl[512], Wr[512];
    for (int i = threadIdx.x; i < 512; i += 256) {
        Wl[i] = W2l[i];
        Wr[i] = W2r[i];
    }
    __syncthreads();

    int wid  = threadIdx.x >> 6;
    int lane = threadIdx.x & 63;
    int g = lane >> 3;          // edge slot 0..7
    int l = lane & 7;           // feature block 0..7
    int n = blockIdx.x * 4 + wid;
    if (n >= N) return;
    int beg = row_ptr[n], end = row_ptr[n + 1];

    float a0[8] = {}, a1[8] = {};   // feats l*8+j and 64+l*8+j
    for (int eb = beg; eb < end; eb += 64) {
        int cnt = min(64, end - eb);
        int id = (eb + lane < end) ? csr_src[eb + lane] : 0;
        for (int t = 0; t < cnt; t += 8) {
            int src = __shfl(id, t + g);
            if (t + g < cnt) {
                const __bf16* row = pq + (size_t)src * 256;
                uint4 w0 = *(const uint4*)(row + l * 8);
                uint4 w1 = *(const uint4*)(row + 64 + l * 8);
                a0[0] += bf16_lo(w0.x); a0[1] += bf16_hi(w0.x);
                a0[2] += bf16_lo(w0.y); a0[3] += bf16_hi(w0.y);
                a0[4] += bf16_lo(w0.z); a0[5] += bf16_hi(w0.z);
                a0[6] += bf16_lo(w0.w); a0[7] += bf16_hi(w0.w);
                a1[0] += bf16_lo(w1.x); a1[1] += bf16_hi(w1.x);
                a1[2] += bf16_lo(w1.y); a1[3] += bf16_hi(w1.y);
                a1[4] += bf16_lo(w1.z); a1[5] += bf16_hi(w1.z);
                a1[6] += bf16_lo(w1.w); a1[7] += bf16_hi(w1.w);
            }
        }
    }
    #pragma unroll
    for (int c = 0; c < 8; ++c) {
        a0[c] += __shfl_xor(a0[c], 8);  a1[c] += __shfl_xor(a1[c], 8);
        a0[c] += __shfl_xor(a0[c], 16); a1[c] += __shfl_xor(a1[c], 16);
        a0[c] += __shfl_xor(a0[c], 32); a1[c] += __shfl_xor(a1[c], 32);
    }

    float inv = 1.0f / fmaxf((float)(end - beg), 1.0f);
    const __bf16* qrow = pq + (size_t)n * 256 + 128;
    uint4  qw0 = *(const uint4*)(qrow + l * 8);
    uint4  qw1 = *(const uint4*)(qrow + 64 + l * 8);
    float4 bv00 = *(const float4*)(b1 + l * 8);
    float4 bv01 = *(const float4*)(b1 + l * 8 + 4);
    float4 bv10 = *(const float4*)(b1 + 64 + l * 8);
    float4 bv11 = *(const float4*)(b1 + 64 + l * 8 + 4);
    float h0[8], h1[8];
    h0[0] = fmaxf(a0[0] * inv + bv00.x + bf16_lo(qw0.x), 0.f);
    h0[1] = fmaxf(a0[1] * inv + bv00.y + bf16_hi(qw0.x), 0.f);
    h0[2] = fmaxf(a0[2] * inv + bv00.z + bf16_lo(qw0.y), 0.f);
    h0[3] = fmaxf(a0[3] * inv + bv00.w + bf16_hi(qw0.y), 0.f);
    h0[4] = fmaxf(a0[4] * inv + bv01.x + bf16_lo(qw0.z), 0.f);
    h0[5] = fmaxf(a0[5] * inv + bv01.y + bf16_hi(qw0.z), 0.f);
    h0[6] = fmaxf(a0[6] * inv + bv01.z + bf16_lo(qw0.w), 0.f);
    h0[7] = fmaxf(a0[7] * inv + bv01.w + bf16_hi(qw0.w), 0.f);
    h1[0] = fmaxf(a1[0] * inv + bv10.x + bf16_lo(qw1.x), 0.f);
    h1[1] = fmaxf(a1[1] * inv + bv10.y + bf16_hi(qw1.x), 0.f);
    h1[2] = fmaxf(a1[2] * inv + bv10.z + bf16_lo(qw1.y), 0.f);
    h1[3] = fmaxf(a1[3] * inv + bv10.w + bf16_hi(qw1.y), 0.f);
    h1[4] = fmaxf(a1[4] * inv + bv11.x + bf16_lo(qw1.z), 0.f);
    h1[5] = fmaxf(a1[5] * inv + bv11.y + bf16_hi(qw1.z), 0.f);
    h1[6] = fmaxf(a1[6] * inv + bv11.z + bf16_lo(qw1.w), 0.f);
    h1[7] = fmaxf(a1[7] * inv + bv11.w + bf16_hi(qw1.w), 0.f);

    float part[8];
    #pragma unroll
    for (int c = 0; c < 4; ++c) {
        float pl = 0.f, pr = 0.f;
        #pragma unroll
        for (int j = 0; j < 8; ++j) {
            pl = fmaf(h0[j], Wl[c * 128 + l * 8 + j], pl);
            pl = fmaf(h1[j], Wl[c * 128 + 64 + l * 8 + j], pl);
            pr = fmaf(h0[j], Wr[c * 128 + l * 8 + j], pr);
            pr = fmaf(h1[j], Wr[c * 128 + 64 + l * 8 + j], pr);
        }
        part[c] = pl; part[4 + c] = pr;
    }
    #pragma unroll
    for (int off = 4; off; off >>= 1)
        #pragma unroll
        for (int c = 0; c < 8; ++c)
            part[c] += __shfl_xor(part[c], off);
    if (lane == 0) {
        *(float4*)(r + (size_t)n * 4) = make_float4(part[0], part[1], part[2], part[3]);
        *(float4*)(s + (size_t)n * 4) = make_float4(part[4], part[5], part[6], part[7]);
    }
}

// ---- layer 2: out[n] = mean_{src} r[src] + b2 + s[n]
__global__ __launch_bounds__(256)
void sage2_gather(const int* __restrict__ row_ptr, const int* __restrict__ csr_src,
                  const float* __restrict__ r, const float* __restrict__ s,
                  const float* __restrict__ b2, float* __restrict__ out, int N)
{
    int t = blockIdx.x * 256 + threadIdx.x;
    if (t >= N * 4) return;
    int n = t >> 2, c = t & 3;
    int beg = row_ptr[n], end = row_ptr[n + 1];
    float acc = 0.f;
    for (int e = beg; e < end; ++e)
        acc += r[(size_t)csr_src[e] * 4 + c];
    out[t] = acc / fmaxf((float)(end - beg), 1.0f) + b2[c] + s[t];
}

extern "C" void kernel_launch(void* const* d_in, const int* in_sizes, int n_in,
                              void* d_out, int out_size, void* d_ws, size_t ws_size,
                              hipStream_t stream)
{
    const float* x   = (const float*)d_in[0];
    const int*   ei  = (const int*)d_in[1];
    const float* W1l = (const float*)d_in[2];
    const float* b1l = (const float*)d_in[3];
    const float* W1r = (const float*)d_in[4];
    const float* W2l = (const float*)d_in[5];
    const float* b2l = (const float*)d_in[6];
    const float* W2r = (const float*)d_in[7];
    float* out = (float*)d_out;

    const int N = in_sizes[0] / 768;   // 50000
    const int E = in_sizes[1] / 2;     // 800000
    const int NB = (N + 1023) / 1024;  // 49 scan blocks
    const int mtiles = (N + 63) / 64;  // 782 gemm tiles

    char* ws = (char*)d_ws;
    size_t off = 0;
    auto alloc = [&](size_t bytes) -> void* {
        void* pp = ws + off;
        off += (bytes + 255) & ~(size_t)255;
        return pp;
    };
    __bf16* pq      = (__bf16*)alloc((size_t)N * 256 * 2);
    float*  r       = (float*)alloc((size_t)N * 4 * 4);
    float*  s       = (float*)alloc((size_t)N * 4 * 4);
    __bf16* Bp      = (__bf16*)alloc((size_t)256 * 768 * 2);
    int*    deg     = (int*)alloc((size_t)N * 4);
    int*    row_ptr = (int*)alloc((size_t)(N + 1) * 4);
    int*    cursor  = (int*)alloc((size_t)N * 4);
    int*    csr_src = (int*)alloc((size_t)E * 4);
    int*    partials= (int*)alloc((size_t)64 * 4);

    // ---- pack W fragment-major + zero deg
    prep<<<(256 * 768 + 255) / 256, 256, 0, stream>>>(W1l, W1r, Bp, deg, N);

    // ---- CSR: count + scans (fill happens inside gemm_fill)
    csr_count<<<(E + 255) / 256, 256, 0, stream>>>(ei, deg, E);
    scan1<<<NB, 1024, 0, stream>>>(deg, row_ptr, partials, N);
    scan23<<<NB, 1024, 0, stream>>>(row_ptr, cursor, partials, N, E, NB);

    // ---- fused layer-1 projection (bf16 MFMA, fp32 async-staged) + csr_fill
    gemm_fill<<<mtiles + 256, 512, 0, stream>>>(x, Bp, pq, N, mtiles,
                                                ei, cursor, csr_src, E);

    // ---- layer 1 aggregate + epilogue + layer-2 projection (fused)
    sage1_fused<<<(N + 3) / 4, 256, 0, stream>>>(row_ptr, csr_src, pq, b1l,
                                                 W2l, W2r, r, s, N);

    // ---- layer 2 aggregate + epilogue
    sage2_gather<<<(N * 4 + 255) / 256, 256, 0, stream>>>(row_ptr, csr_src, r, s, b2l, out, N);
}

// Round 13
// 202.940 us; speedup vs baseline: 1.0680x; 1.0041x over previous
//
#include <hip/hip_runtime.h>

// ---------------------------------------------------------------------------
// TextGraphSAGE: 2-layer SAGEConv (mean aggr), N=50000, D=768, H=128, C=4,
// E=800000.
//  - project BEFORE aggregating (mean commutes with linear map)
//  - CSR gather instead of scatter atomics (r1: 102M float atomics = 77%)
//  - r10-r12 lesson: the LDS staging path runs at ~1.3TB/s regardless of
//    pipeline structure (dbuf/counted-vmcnt/gload_lds all neutral) -- EXCEPT
//    r6's small-block config which hit 3.36TB/s. The lever is occupancy:
//    many small resident blocks, not pipelining inside one block.
//  - r13: BM=32 / BN=256 / 256-thread blocks, 9KB LDS -> ~8 blocks/CU.
//    Reg-staged fp32->bf16 (no cvt pass), ONE barrier per K-tile (double
//    buffer), B fragment-direct from L2. K-order unchanged (bit-identical).
// ---------------------------------------------------------------------------

typedef __bf16 bf16x8 __attribute__((ext_vector_type(8)));
typedef float  f32x4  __attribute__((ext_vector_type(4)));

__device__ __forceinline__ float bf16_lo(uint32_t w) {
    union { uint32_t u; float f; } c; c.u = w << 16; return c.f;
}
__device__ __forceinline__ float bf16_hi(uint32_t w) {
    union { uint32_t u; float f; } c; c.u = w & 0xffff0000u; return c.f;
}

// ---- prep: pack W into fragment-major bf16 Bp[kg][col][8] (kg=k/8, 96x256x8)
//      element (col,k) -> Bp[(k>>3)*2048 + col*8 + (k&7)]; also zero deg.
__global__ __launch_bounds__(256)
void prep(const float* __restrict__ W1l, const float* __restrict__ W1r,
          __bf16* __restrict__ Bp, int* __restrict__ deg, int N)
{
    int i = blockIdx.x * 256 + threadIdx.x;
    if (i < N) deg[i] = 0;
    if (i < 256 * 768) {
        int col = i / 768, k = i - col * 768;
        float v = (col < 128) ? W1l[col * 768 + k] : W1r[(col - 128) * 768 + k];
        Bp[((k >> 3) << 11) + (col << 3) + (k & 7)] = (__bf16)v;
    }
}

// ---- CSR build step 1: degree histogram
__global__ __launch_bounds__(256)
void csr_count(const int* __restrict__ ei, int* __restrict__ deg, int E)
{
    int e = blockIdx.x * 256 + threadIdx.x;
    if (e >= E) return;
    atomicAdd(&deg[ei[E + e]], 1);
}

// ---- scan step 1: per-1024-block exclusive scan + block totals
__global__ __launch_bounds__(1024)
void scan1(const int* __restrict__ deg, int* __restrict__ row_ptr,
           int* __restrict__ partials, int N)
{
    __shared__ int buf[1024];
    int i = blockIdx.x * 1024 + threadIdx.x;
    int v = (i < N) ? deg[i] : 0;
    int val = v;
    buf[threadIdx.x] = val;
    __syncthreads();
    for (int off = 1; off < 1024; off <<= 1) {
        int t = (threadIdx.x >= (unsigned)off) ? buf[threadIdx.x - off] : 0;
        __syncthreads();
        val += t;
        buf[threadIdx.x] = val;
        __syncthreads();
    }
    if (i < N) row_ptr[i] = val - v;
    if (threadIdx.x == 1023) partials[blockIdx.x] = val;
}

// ---- scan steps 2+3 merged
__global__ __launch_bounds__(1024)
void scan23(int* __restrict__ row_ptr, int* __restrict__ cursor,
            const int* __restrict__ partials, int N, int E, int nb)
{
    __shared__ int soff;
    int b = blockIdx.x;
    if (threadIdx.x < 64) {
        int lane = threadIdx.x;
        int v = (lane < nb) ? partials[lane] : 0;
        int s = v;
        #pragma unroll
        for (int off = 1; off < 64; off <<= 1) {
            int t = __shfl_up(s, off);
            if (lane >= off) s += t;
        }
        if (lane == b) soff = s - v;
    }
    __syncthreads();
    int off = soff;
    int i = b * 1024 + threadIdx.x;
    if (i < N) {
        int v = row_ptr[i] + off;
        row_ptr[i] = v;
        cursor[i]  = v;
    }
    if (b == 0 && threadIdx.x == 0) row_ptr[N] = E;
}

// ---- fused: gemm tiles (blocks < mtiles) + csr_fill (blocks >= mtiles).
// gemm: pq[M][256](bf16) = x[M][768](f32) @ W[256][768]^T.
// 32x256 tile, 256 threads (4 waves, wave-tile 32x64), BK=64, 12 K-tiles.
// A reg-staged (fp32 load -> cvt -> ds_write_b128) into As[2][32][72] bf16
// (9KB, +8 pad = bank-minimal for both write and read). ONE barrier/tile.
// B fragment-direct from L2-resident packed Bp. ~8 blocks/CU resident.
__global__ __launch_bounds__(256)
void gemm_fill(const float* __restrict__ x, const __bf16* __restrict__ Bp,
               __bf16* __restrict__ Cb, int M, int mtiles,
               const int* __restrict__ ei, int* __restrict__ cursor,
               int* __restrict__ csr_src, int E)
{
    __shared__ __bf16 As[2][32][72];         // 9.2 KB
    const int tid = threadIdx.x;

    if ((int)blockIdx.x >= mtiles) {
        // ---------------- csr_fill path ----------------
        int stride = (gridDim.x - mtiles) * 256;
        for (int e = (blockIdx.x - mtiles) * 256 + tid; e < E; e += stride) {
            int src = ei[e];
            int dst = ei[E + e];
            int pos = atomicAdd(&cursor[dst], 1);
            csr_src[pos] = src;
        }
        return;
    }

    // ---------------- gemm path ----------------
    const int bm   = blockIdx.x * 32;
    const int lane = tid & 63;
    const int wc   = tid >> 6;               // 0..3: wave owns cols wc*64..+63
    const int l15  = lane & 15;
    const int lk   = lane >> 4;              // 0..3

    f32x4 acc[2][4] = {};

    // staging map: thread t covers row t>>3 (0..31), cols (t&7)*8..+7
    const int srow = tid >> 3;
    const int scol = (tid & 7) << 3;
    const float* gsrc = x + (size_t)min(bm + srow, M - 1) * 768 + scol;
    // clamped rows duplicate row M-1 (never stored)

    const __bf16* bbase = Bp + ((size_t)(wc * 64 + l15) << 3) + ((size_t)lk << 11);

    float4 ap0, ap1;
    auto load_A = [&](int k0) {
        ap0 = *(const float4*)(gsrc + k0);
        ap1 = *(const float4*)(gsrc + k0 + 4);
    };

    load_A(0);
    for (int kt = 0; kt < 12; ++kt) {
        const int buf = kt & 1;
        {   // convert + stage into LDS buf
            bf16x8 b;
            b[0] = (__bf16)ap0.x; b[1] = (__bf16)ap0.y;
            b[2] = (__bf16)ap0.z; b[3] = (__bf16)ap0.w;
            b[4] = (__bf16)ap1.x; b[5] = (__bf16)ap1.y;
            b[6] = (__bf16)ap1.z; b[7] = (__bf16)ap1.w;
            *(bf16x8*)&As[buf][srow][scol] = b;
        }
        __syncthreads();                     // buf ready; prev buf's readers
                                             // finished before their write
        if (kt < 11) load_A((kt + 1) * 64);  // prefetch in flight across MFMA

        #pragma unroll
        for (int ks = 0; ks < 2; ++ks) {
            bf16x8 bcur[4];
            #pragma unroll
            for (int j = 0; j < 4; ++j)
                bcur[j] = *(const bf16x8*)(bbase +
                    (((size_t)(kt * 8 + ks * 4) << 11) + ((size_t)j << 7)));
            bf16x8 af[2];
            #pragma unroll
            for (int i = 0; i < 2; ++i)
                af[i] = *(const bf16x8*)&As[buf][i * 16 + l15][ks * 32 + lk * 8];
            #pragma unroll
            for (int i = 0; i < 2; ++i)
                #pragma unroll
                for (int j = 0; j < 4; ++j)
                    acc[i][j] = __builtin_amdgcn_mfma_f32_16x16x32_bf16(
                        af[i], bcur[j], acc[i][j], 0, 0, 0);
        }
    }

    // C/D layout: col = lane&15, row = (lane>>4)*4 + reg  [m89-verified]
    #pragma unroll
    for (int i = 0; i < 2; ++i)
        #pragma unroll
        for (int j = 0; j < 4; ++j)
            #pragma unroll
            for (int v = 0; v < 4; ++v) {
                int row = bm + i * 16 + lk * 4 + v;
                int col = wc * 64 + j * 16 + l15;
                if (row < M) Cb[(size_t)row * 256 + col] = (__bf16)acc[i][j][v];
            }
}

// ---- layer 1 + layer-2 projection, fused. One wave per node.
// 8 lanes per edge x 32B/lane (2 x uint4) -> 8 edges in flight / iteration.
__global__ __launch_bounds__(256)
void sage1_fused(const int* __restrict__ row_ptr, const int* __restrict__ csr_src,
                 const __bf16* __restrict__ pq, const float* __restrict__ b1,
                 const float* __restrict__ W2l, const float* __restrict__ W2r,
                 float* __restrict__ r, float* __restrict__ s, int N)
{
    __shared__ float Wl[512], Wr[512];
    for (int i = threadIdx.x; i < 512; i += 256) {
        Wl[i] = W2l[i];
        Wr[i] = W2r[i];
    }
    __syncthreads();

    int wid  = threadIdx.x >> 6;
    int lane = threadIdx.x & 63;
    int g = lane >> 3;          // edge slot 0..7
    int l = lane & 7;           // feature block 0..7
    int n = blockIdx.x * 4 + wid;
    if (n >= N) return;
    int beg = row_ptr[n], end = row_ptr[n + 1];

    float a0[8] = {}, a1[8] = {};   // feats l*8+j and 64+l*8+j
    for (int eb = beg; eb < end; eb += 64) {
        int cnt = min(64, end - eb);
        int id = (eb + lane < end) ? csr_src[eb + lane] : 0;
        for (int t = 0; t < cnt; t += 8) {
            int src = __shfl(id, t + g);
            if (t + g < cnt) {
                const __bf16* row = pq + (size_t)src * 256;
                uint4 w0 = *(const uint4*)(row + l * 8);
                uint4 w1 = *(const uint4*)(row + 64 + l * 8);
                a0[0] += bf16_lo(w0.x); a0[1] += bf16_hi(w0.x);
                a0[2] += bf16_lo(w0.y); a0[3] += bf16_hi(w0.y);
                a0[4] += bf16_lo(w0.z); a0[5] += bf16_hi(w0.z);
                a0[6] += bf16_lo(w0.w); a0[7] += bf16_hi(w0.w);
                a1[0] += bf16_lo(w1.x); a1[1] += bf16_hi(w1.x);
                a1[2] += bf16_lo(w1.y); a1[3] += bf16_hi(w1.y);
                a1[4] += bf16_lo(w1.z); a1[5] += bf16_hi(w1.z);
                a1[6] += bf16_lo(w1.w); a1[7] += bf16_hi(w1.w);
            }
        }
    }
    #pragma unroll
    for (int c = 0; c < 8; ++c) {
        a0[c] += __shfl_xor(a0[c], 8);  a1[c] += __shfl_xor(a1[c], 8);
        a0[c] += __shfl_xor(a0[c], 16); a1[c] += __shfl_xor(a1[c], 16);
        a0[c] += __shfl_xor(a0[c], 32); a1[c] += __shfl_xor(a1[c], 32);
    }

    float inv = 1.0f / fmaxf((float)(end - beg), 1.0f);
    const __bf16* qrow = pq + (size_t)n * 256 + 128;
    uint4  qw0 = *(const uint4*)(qrow + l * 8);
    uint4  qw1 = *(const uint4*)(qrow + 64 + l * 8);
    float4 bv00 = *(const float4*)(b1 + l * 8);
    float4 bv01 = *(const float4*)(b1 + l * 8 + 4);
    float4 bv10 = *(const float4*)(b1 + 64 + l * 8);
    float4 bv11 = *(const float4*)(b1 + 64 + l * 8 + 4);
    float h0[8], h1[8];
    h0[0] = fmaxf(a0[0] * inv + bv00.x + bf16_lo(qw0.x), 0.f);
    h0[1] = fmaxf(a0[1] * inv + bv00.y + bf16_hi(qw0.x), 0.f);
    h0[2] = fmaxf(a0[2] * inv + bv00.z + bf16_lo(qw0.y), 0.f);
    h0[3] = fmaxf(a0[3] * inv + bv00.w + bf16_hi(qw0.y), 0.f);
    h0[4] = fmaxf(a0[4] * inv + bv01.x + bf16_lo(qw0.z), 0.f);
    h0[5] = fmaxf(a0[5] * inv + bv01.y + bf16_hi(qw0.z), 0.f);
    h0[6] = fmaxf(a0[6] * inv + bv01.z + bf16_lo(qw0.w), 0.f);
    h0[7] = fmaxf(a0[7] * inv + bv01.w + bf16_hi(qw0.w), 0.f);
    h1[0] = fmaxf(a1[0] * inv + bv10.x + bf16_lo(qw1.x), 0.f);
    h1[1] = fmaxf(a1[1] * inv + bv10.y + bf16_hi(qw1.x), 0.f);
    h1[2] = fmaxf(a1[2] * inv + bv10.z + bf16_lo(qw1.y), 0.f);
    h1[3] = fmaxf(a1[3] * inv + bv10.w + bf16_hi(qw1.y), 0.f);
    h1[4] = fmaxf(a1[4] * inv + bv11.x + bf16_lo(qw1.z), 0.f);
    h1[5] = fmaxf(a1[5] * inv + bv11.y + bf16_hi(qw1.z), 0.f);
    h1[6] = fmaxf(a1[6] * inv + bv11.z + bf16_lo(qw1.w), 0.f);
    h1[7] = fmaxf(a1[7] * inv + bv11.w + bf16_hi(qw1.w), 0.f);

    float part[8];
    #pragma unroll
    for (int c = 0; c < 4; ++c) {
        float pl = 0.f, pr = 0.f;
        #pragma unroll
        for (int j = 0; j < 8; ++j) {
            pl = fmaf(h0[j], Wl[c * 128 + l * 8 + j], pl);
            pl = fmaf(h1[j], Wl[c * 128 + 64 + l * 8 + j], pl);
            pr = fmaf(h0[j], Wr[c * 128 + l * 8 + j], pr);
            pr = fmaf(h1[j], Wr[c * 128 + 64 + l * 8 + j], pr);
        }
        part[c] = pl; part[4 + c] = pr;
    }
    #pragma unroll
    for (int off = 4; off; off >>= 1)
        #pragma unroll
        for (int c = 0; c < 8; ++c)
            part[c] += __shfl_xor(part[c], off);
    if (lane == 0) {
        *(float4*)(r + (size_t)n * 4) = make_float4(part[0], part[1], part[2], part[3]);
        *(float4*)(s + (size_t)n * 4) = make_float4(part[4], part[5], part[6], part[7]);
    }
}

// ---- layer 2: out[n] = mean_{src} r[src] + b2 + s[n]
__global__ __launch_bounds__(256)
void sage2_gather(const int* __restrict__ row_ptr, const int* __restrict__ csr_src,
                  const float* __restrict__ r, const float* __restrict__ s,
                  const float* __restrict__ b2, float* __restrict__ out, int N)
{
    int t = blockIdx.x * 256 + threadIdx.x;
    if (t >= N * 4) return;
    int n = t >> 2, c = t & 3;
    int beg = row_ptr[n], end = row_ptr[n + 1];
    float acc = 0.f;
    for (int e = beg; e < end; ++e)
        acc += r[(size_t)csr_src[e] * 4 + c];
    out[t] = acc / fmaxf((float)(end - beg), 1.0f) + b2[c] + s[t];
}

extern "C" void kernel_launch(void* const* d_in, const int* in_sizes, int n_in,
                              void* d_out, int out_size, void* d_ws, size_t ws_size,
                              hipStream_t stream)
{
    const float* x   = (const float*)d_in[0];
    const int*   ei  = (const int*)d_in[1];
    const float* W1l = (const float*)d_in[2];
    const float* b1l = (const float*)d_in[3];
    const float* W1r = (const float*)d_in[4];
    const float* W2l = (const float*)d_in[5];
    const float* b2l = (const float*)d_in[6];
    const float* W2r = (const float*)d_in[7];
    float* out = (float*)d_out;

    const int N = in_sizes[0] / 768;   // 50000
    const int E = in_sizes[1] / 2;     // 800000
    const int NB = (N + 1023) / 1024;  // 49 scan blocks
    const int mtiles = (N + 31) / 32;  // 1563 gemm tiles

    char* ws = (char*)d_ws;
    size_t off = 0;
    auto alloc = [&](size_t bytes) -> void* {
        void* pp = ws + off;
        off += (bytes + 255) & ~(size_t)255;
        return pp;
    };
    __bf16* pq      = (__bf16*)alloc((size_t)N * 256 * 2);
    float*  r       = (float*)alloc((size_t)N * 4 * 4);
    float*  s       = (float*)alloc((size_t)N * 4 * 4);
    __bf16* Bp      = (__bf16*)alloc((size_t)256 * 768 * 2);
    int*    deg     = (int*)alloc((size_t)N * 4);
    int*    row_ptr = (int*)alloc((size_t)(N + 1) * 4);
    int*    cursor  = (int*)alloc((size_t)N * 4);
    int*    csr_src = (int*)alloc((size_t)E * 4);
    int*    partials= (int*)alloc((size_t)64 * 4);

    // ---- pack W fragment-major + zero deg
    prep<<<(256 * 768 + 255) / 256, 256, 0, stream>>>(W1l, W1r, Bp, deg, N);

    // ---- CSR: count + scans (fill happens inside gemm_fill)
    csr_count<<<(E + 255) / 256, 256, 0, stream>>>(ei, deg, E);
    scan1<<<NB, 1024, 0, stream>>>(deg, row_ptr, partials, N);
    scan23<<<NB, 1024, 0, stream>>>(row_ptr, cursor, partials, N, E, NB);

    // ---- fused layer-1 projection (bf16 MFMA, high-occupancy small blocks)
    //      + csr_fill (independent chains overlap in one dispatch)
    gemm_fill<<<mtiles + 256, 256, 0, stream>>>(x, Bp, pq, N, mtiles,
                                                ei, cursor, csr_src, E);

    // ---- layer 1 aggregate + epilogue + layer-2 projection (fused)
    sage1_fused<<<(N + 3) / 4, 256, 0, stream>>>(row_ptr, csr_src, pq, b1l,
                                                 W2l, W2r, r, s, N);

    // ---- layer 2 aggregate + epilogue
    sage2_gather<<<(N * 4 + 255) / 256, 256, 0, stream>>>(row_ptr, csr_src, r, s, b2l, out, N);
}